// Round 4
// baseline (1130.836 us; speedup 1.0000x reference)
//
#include <hip/hip_runtime.h>
#include <cstdint>

#define NVEH  4096
#define NT    1024
#define INW   12
#define UNITS 20

typedef float f32x2 __attribute__((ext_vector_type(2)));

#define PIN(v)  asm volatile("" : "+v"(v))

// Packed dual-FMA (VOP3P): acc.lo += w.lo * s, acc.hi += w.hi * s
// where s is the LOW half of the pair operand (op_sel_hi[src1]=0 broadcasts lo).
#define PKFMA_LO(acc, w, s2) \
    asm("v_pk_fma_f32 %0, %1, %2, %0 op_sel:[0,0,0] op_sel_hi:[1,0,1]" \
        : "+v"(acc) : "v"(w), "v"(s2))
// Same but broadcasting the HIGH half of the pair operand.
#define PKFMA_HI(acc, w, s2) \
    asm("v_pk_fma_f32 %0, %1, %2, %0 op_sel:[0,1,0] op_sel_hi:[1,1,1]" \
        : "+v"(acc) : "v"(w), "v"(s2))
// Packed mul, broadcasting low half of src1 (chain-head init, saves movs)
#define PKMUL_LO(dst, w, s2) \
    asm("v_pk_mul_f32 %0, %1, %2 op_sel:[0,0] op_sel_hi:[1,0]" \
        : "=v"(dst) : "v"(w), "v"(s2))
// Full element-wise packed fma: acc += a * b (both halves independent)
#define PKFMA(acc, a, b) \
    asm("v_pk_fma_f32 %0, %1, %2, %0" : "+v"(acc) : "v"(a), "v"(b))

__device__ __forceinline__ float fexp2(float x) { return __builtin_amdgcn_exp2f(x); }
__device__ __forceinline__ float frcp(float x)  { return __builtin_amdgcn_rcpf(x); }

// async global -> LDS, 16B per active lane, dest = uniform base + lane*16
__device__ __forceinline__ void gload_lds16(const float* g, float* l) {
    __builtin_amdgcn_global_load_lds(
        (const __attribute__((address_space(1))) unsigned int*)g,
        (__attribute__((address_space(3))) unsigned int*)l,
        16, 0, 0);
}

__global__ __attribute__((amdgpu_waves_per_eu(2, 2))) __launch_bounds__(64)
void rnncf_kernel(const float* __restrict__ x,          // (NVEH, NT, 12)
                  const float* __restrict__ init_state, // (NVEH, 2)
                  const float* __restrict__ hs,         // (2, NVEH, 20)
                  const float* __restrict__ K,          // (12, 80)
                  const float* __restrict__ R,          // (20, 80)
                  const float* __restrict__ bias,       // (80)
                  const float* __restrict__ W2,         // (20, 10)
                  const float* __restrict__ b2,         // (10)
                  const float* __restrict__ Wlc,        // (10, 3)
                  const float* __restrict__ blc,        // (3)
                  const float* __restrict__ W1,         // (10, 1)
                  const float* __restrict__ b1,         // (1)
                  float* __restrict__ out)
{
    const int lane = threadIdx.x;
    const int grp  = lane / 20;     // 0..2 = vehicle slot, 3 = idle lanes 60..63
    const int sub  = lane % 20;     // unit index / head index
    const int veh  = blockIdx.x * 3 + grp;
    const bool active = (grp < 3) && (veh < NVEH);
    const int vs = active ? veh : 0;

    __shared__ __align__(16) float x_lds[8][4][12];   // depth-8 x FIFO
    __shared__ __align__(16) float h_lds[4][20];
    __shared__ __align__(16) float x2_lds[4][12];
    // streamed weight tables (constant after init; per-step ds_read_b64,
    // broadcast across the 3 groups -> ~2 LDS clk each, conflict-free)
    __shared__ __align__(16) f32x2 ks01l[14][20];  // rows 0..11: KS pairs (i,f);
    __shared__ __align__(16) f32x2 ks23l[14][20];  // row 12: bias, row 13: kd
    __shared__ __align__(16) f32x2 w2l[10][10];    // [mh][u] = {W2[2u][mh],W2[2u+1][mh]}
    __shared__ __align__(16) f32x2 wlcl[5][3];     // [m][j]

    // gate exp2 pre-scale constants: i,f,o -> -log2(e), g -> +2*log2(e)
    const float s01l = -1.4426950408889634f;   // i
    const float s01h = -1.4426950408889634f;   // f
    const float s23l =  2.8853900817779268f;   // g
    const float s23h = -1.4426950408889634f;   // o

    // ---- build LDS weight tables (once) ----
    for (int idx = lane; idx < 240; idx += 64) {
        int k = idx / 20, s = idx % 20;
        float coef = (k < 3) ? 0.01f : (k < 6) ? -0.01f : 0.025f;
        f32x2 a, b;
        a[0] = s01l * coef * K[k * 80 + s];
        a[1] = s01h * coef * K[k * 80 + 20 + s];
        b[0] = s23l * coef * K[k * 80 + 40 + s];
        b[1] = s23h * coef * K[k * 80 + 60 + s];
        ks01l[k][s] = a; ks23l[k][s] = b;
    }
    if (lane < 20) {
        float a0 = 0, a1 = 0, a2 = 0, a3 = 0;
        for (int k = 0; k < 6; ++k) {
            float sgn = (k < 3) ? -0.01f : 0.01f;
            a0 += sgn * K[k * 80 + lane];
            a1 += sgn * K[k * 80 + 20 + lane];
            a2 += sgn * K[k * 80 + 40 + lane];
            a3 += sgn * K[k * 80 + 60 + lane];
        }
        f32x2 kd01, kd23, bz01, bz23;
        kd01[0] = s01l * a0; kd01[1] = s01h * a1;
        kd23[0] = s23l * a2; kd23[1] = s23h * a3;
        bz01[0] = s01l * bias[lane];      bz01[1] = s01h * bias[20 + lane];
        bz23[0] = s23l * bias[40 + lane]; bz23[1] = s23h * bias[60 + lane];
        ks01l[13][lane] = kd01; ks23l[13][lane] = kd23;
        ks01l[12][lane] = bz01; ks23l[12][lane] = bz23;
    }
    for (int idx = lane; idx < 100; idx += 64) {
        int m = idx / 10, u = idx % 10;
        f32x2 w; w[0] = W2[(2 * u) * 10 + m]; w[1] = W2[(2 * u + 1) * 10 + m];
        w2l[m][u] = w;
    }
    if (lane < 15) {
        int m = lane / 3, j = lane % 3;
        f32x2 w; w[0] = Wlc[(2 * m) * 3 + j]; w[1] = Wlc[(2 * m + 1) * 3 + j];
        wlcl[m][j] = w;
    }
    __builtin_amdgcn_wave_barrier();

    // ---- R stays in registers (chain-critical, 40 pairs) ----
    f32x2 R01[20], R23[20];
#pragma unroll
    for (int k = 0; k < 20; ++k) {
        R01[k][0] = s01l * R[k * 80 + sub];      R01[k][1] = s01h * R[k * 80 + 20 + sub];
        R23[k][0] = s23l * R[k * 80 + 40 + sub]; R23[k][1] = s23h * R[k * 80 + 60 + sub];
    }
#pragma unroll
    for (int k = 0; k < 20; ++k) { PIN(R01[k]); PIN(R23[k]); }

    const int mh = (sub < 10) ? sub : 9;
    const int jl = (sub < 3) ? sub : 0;
    float b2s  = b2[mh];
    float blcs = blc[jl];
    PIN(b2s); PIN(blcs);

    // ---- state ----
    float pos = init_state[vs * 2 + 0];
    float spd = init_state[vs * 2 + 1];
    float c   = hs[(size_t)NVEH * UNITS + (size_t)vs * UNITS + sub];
    float hnew = hs[(size_t)vs * UNITS + sub];

    h_lds[grp][sub] = hnew;
    __builtin_amdgcn_wave_barrier();
    f32x2 hrp[10];
#pragma unroll
    for (int q = 0; q < 5; ++q) {
        float4 v = ((const float4*)&h_lds[grp][0])[q];
        hrp[2*q][0]   = v.x; hrp[2*q][1]   = v.y;
        hrp[2*q+1][0] = v.z; hrp[2*q+1][1] = v.w;
    }
    __builtin_amdgcn_wave_barrier();

    // ---- deep x FIFO: lanes 0..8 stage 16B/step directly into LDS ----
    const bool stg = (lane < 9);
    int sveh = blockIdx.x * 3 + lane / 3;
    if (sveh > NVEH - 1) sveh = NVEH - 1;
    const float* sgp = x + (size_t)sveh * NT * INW + (lane % 3) * 4;

    if (stg) {
#pragma unroll
        for (int t0 = 0; t0 < 8; ++t0)
            gload_lds16(sgp + (size_t)t0 * INW, &x_lds[t0][0][0]);
    }

    float* trajp = out + (size_t)vs * NT;
    float* lcp   = out + (size_t)NVEH * NT + (size_t)vs * NT * 3;

    for (int tb = 0; tb < NT; tb += 4) {
        // loads for steps tb..tb+3 were issued >=1 full block ago; allow the
        // newest 4 (next block's loads) to stay in flight. Never drains to 0.
        asm volatile("s_waitcnt vmcnt(4)" ::: "memory");

#pragma unroll
        for (int j = 0; j < 4; ++j) {
            const int t = tb + j;

            // 1. read raw x_t (per-group broadcast) + deferred-head x2 read
            float4 u0 = ((const float4*)&x_lds[t & 7][grp][0])[0];
            float4 u1 = ((const float4*)&x_lds[t & 7][grp][0])[1];
            float4 u2 = ((const float4*)&x_lds[t & 7][grp][0])[2];
            f32x2 x2p[5];
            if (t > 0) {
#pragma unroll
                for (int q = 0; q < 5; ++q)
                    x2p[q] = ((const f32x2*)&x2_lds[grp][0])[q];
            }
            __builtin_amdgcn_wave_barrier();

            f32x2 xp[6];
            xp[0][0] = u0.x; xp[0][1] = u0.y;
            xp[1][0] = u0.z; xp[1][1] = u0.w;
            xp[2][0] = u1.x; xp[2][1] = u1.y;
            xp[3][0] = u1.z; xp[3][1] = u1.w;
            xp[4][0] = u2.x; xp[4][1] = u2.y;
            xp[5][0] = u2.z; xp[5][1] = u2.w;

            // 2. zK = bias + pos*kd + KS.x_raw  (KS streamed from LDS; the
            //    ds_read latency hides under the register-resident zA/zB chains)
            f32x2 posp; posp[0] = pos; posp[1] = pos;
            f32x2 zK01 = ks01l[12][sub] + ks01l[13][sub] * posp;
            f32x2 zK23 = ks23l[12][sub] + ks23l[13][sub] * posp;
#pragma unroll
            for (int q = 0; q < 6; ++q) {
                f32x2 ka = ks01l[2*q][sub],  kb = ks01l[2*q+1][sub];
                f32x2 kc = ks23l[2*q][sub],  kd = ks23l[2*q+1][sub];
                PKFMA_LO(zK01, ka, xp[q]);
                PKFMA_LO(zK23, kc, xp[q]);
                PKFMA_HI(zK01, kb, xp[q]);
                PKFMA_HI(zK23, kd, xp[q]);
            }

            // 3. recurrent part: 2 parallel register-fed chains per pair
            f32x2 zA01, zA23, zB01, zB23;
            PKMUL_LO(zA01, R01[0], hrp[0]);
            PKMUL_LO(zA23, R23[0], hrp[0]);
            PKFMA_HI(zA01, R01[1], hrp[0]);
            PKFMA_HI(zA23, R23[1], hrp[0]);
#pragma unroll
            for (int q = 1; q < 5; ++q) {
                PKFMA_LO(zA01, R01[2*q],   hrp[q]);
                PKFMA_LO(zA23, R23[2*q],   hrp[q]);
                PKFMA_HI(zA01, R01[2*q+1], hrp[q]);
                PKFMA_HI(zA23, R23[2*q+1], hrp[q]);
            }
            PKMUL_LO(zB01, R01[10], hrp[5]);
            PKMUL_LO(zB23, R23[10], hrp[5]);
            PKFMA_HI(zB01, R01[11], hrp[5]);
            PKFMA_HI(zB23, R23[11], hrp[5]);
#pragma unroll
            for (int q = 6; q < 10; ++q) {
                PKFMA_LO(zB01, R01[2*q],   hrp[q]);
                PKFMA_LO(zB23, R23[2*q],   hrp[q]);
                PKFMA_HI(zB01, R01[2*q+1], hrp[q]);
                PKFMA_HI(zB23, R23[2*q+1], hrp[q]);
            }
            f32x2 z01 = (zK01 + zA01) + zB01;
            f32x2 z23 = (zK23 + zA23) + zB23;

            // 4. deferred head finish: acc(t-1) -> spd_t (W1/b1 via SGPRs)
            if (t > 0) {
                float a0 = b1[0], a1 = 0.0f;
#pragma unroll
                for (int m = 0; m < 5; ++m) {
                    a0 = fmaf(x2p[m][0], W1[2*m],   a0);
                    a1 = fmaf(x2p[m][1], W1[2*m+1], a1);
                }
                float accr = a0 + a1;
                spd = fmaf(0.1f, fmaf(10.0f, accr, -6.0f), spd);
                if (active && sub < 3) {
                    f32x2 lc2; lc2[0] = blcs; lc2[1] = 0.0f;
#pragma unroll
                    for (int m = 0; m < 5; ++m) {
                        f32x2 w = wlcl[m][jl];
                        PKFMA(lc2, x2p[m], w);
                    }
                    lcp[(t - 1) * 3 + sub] = lc2[0] + lc2[1];
                }
            }

            // 5. cell update (weights pre-scaled: exp2 args ready)
            float ig = frcp(1.0f + fexp2(z01[0]));
            float fg = frcp(1.0f + fexp2(z01[1]));
            float gg = 1.0f - 2.0f * frcp(fexp2(z23[0]) + 1.0f);
            float og = frcp(1.0f + fexp2(z23[1]));
            c = fmaf(fg, c, ig * gg);
            float th = 1.0f - 2.0f * frcp(fexp2(2.8853900817779268f * c) + 1.0f);
            hnew = og * th;

            // 6. pos update + traj output (uses spd_t)
            float posn = fmaf(0.1f, spd, pos);
            if (active && sub == 0) trajp[t] = posn;
            pos = posn;

            // 7. share h_new, reload into packed regs (first in lgkm queue)
            h_lds[grp][sub] = hnew;
            __builtin_amdgcn_wave_barrier();
#pragma unroll
            for (int q = 0; q < 5; ++q) {
                float4 v = ((const float4*)&h_lds[grp][0])[q];
                hrp[2*q][0]   = v.x; hrp[2*q][1]   = v.y;
                hrp[2*q+1][0] = v.z; hrp[2*q+1][1] = v.w;
            }
            __builtin_amdgcn_wave_barrier();

            // 8. head part 1: xm = relu(h . W2[:,mh] + b2[mh]) (W2 streamed)
            f32x2 xm2; xm2[0] = b2s; xm2[1] = 0.0f;
#pragma unroll
            for (int u = 0; u < 10; ++u) {
                f32x2 w = w2l[mh][u];
                PKFMA(xm2, hrp[u], w);
            }
            float xm = fmaxf(xm2[0] + xm2[1], 0.0f);
            if (sub < 10) x2_lds[grp][sub] = xm;
            __builtin_amdgcn_wave_barrier();
        }

        // issue loads for steps tb+8 .. tb+11 into the slots just consumed
        if (stg) {
#pragma unroll
            for (int j = 0; j < 4; ++j) {
                int tt = tb + 8 + j; if (tt > NT - 1) tt = NT - 1;
                gload_lds16(sgp + (size_t)tt * INW, &x_lds[(tb + j) & 7][0][0]);
            }
        }
    }

    // ---- epilogue: finish head for step NT-1 ----
    {
        f32x2 x2p[5];
#pragma unroll
        for (int q = 0; q < 5; ++q)
            x2p[q] = ((const f32x2*)&x2_lds[grp][0])[q];
        float a0 = b1[0], a1 = 0.0f;
#pragma unroll
        for (int m = 0; m < 5; ++m) {
            a0 = fmaf(x2p[m][0], W1[2*m],   a0);
            a1 = fmaf(x2p[m][1], W1[2*m+1], a1);
        }
        float accr = a0 + a1;
        spd = fmaf(0.1f, fmaf(10.0f, accr, -6.0f), spd);
        if (active && sub < 3) {
            f32x2 lc2; lc2[0] = blcs; lc2[1] = 0.0f;
#pragma unroll
            for (int m = 0; m < 5; ++m) {
                f32x2 w = wlcl[m][jl];
                PKFMA(lc2, x2p[m], w);
            }
            lcp[(NT - 1) * 3 + sub] = lc2[0] + lc2[1];
        }
    }

    if (active) {
        float* spdf = out + (size_t)NVEH * NT * 4;
        float* hf   = spdf + NVEH;
        float* cf   = hf + (size_t)NVEH * UNITS;
        if (sub == 0) spdf[veh] = spd;
        hf[(size_t)veh * UNITS + sub] = hnew;
        cf[(size_t)veh * UNITS + sub] = c;
    }
}

extern "C" void kernel_launch(void* const* d_in, const int* in_sizes, int n_in,
                              void* d_out, int out_size, void* d_ws, size_t ws_size,
                              hipStream_t stream) {
    const float* x    = (const float*)d_in[0];
    const float* st0  = (const float*)d_in[1];
    const float* hs   = (const float*)d_in[2];
    const float* K    = (const float*)d_in[3];
    const float* R    = (const float*)d_in[4];
    const float* bias = (const float*)d_in[5];
    const float* W2   = (const float*)d_in[6];
    const float* b2   = (const float*)d_in[7];
    const float* Wlc  = (const float*)d_in[8];
    const float* blc  = (const float*)d_in[9];
    const float* W1   = (const float*)d_in[10];
    const float* b1   = (const float*)d_in[11];
    float* out = (float*)d_out;

    dim3 grid((NVEH + 2) / 3);   // 1366 blocks, 3 vehicles each
    dim3 block(64);
    hipLaunchKernelGGL(rnncf_kernel, grid, block, 0, stream,
                       x, st0, hs, K, R, bias, W2, b2, Wlc, blc, W1, b1, out);
}

// Round 5
// 715.990 us; speedup vs baseline: 1.5794x; 1.5794x over previous
//
#include <hip/hip_runtime.h>
#include <cstdint>

#define NVEH  4096
#define NT    1024
#define INW   12
#define UNITS 20

typedef float f32x2 __attribute__((ext_vector_type(2)));

#define PIN(v)  asm volatile("" : "+v"(v))

// Packed dual-FMA (VOP3P): acc.lo += w.lo * s, acc.hi += w.hi * s
// where s is the LOW half of the pair operand (op_sel_hi[src1]=0 broadcasts lo).
#define PKFMA_LO(acc, w, s2) \
    asm("v_pk_fma_f32 %0, %1, %2, %0 op_sel:[0,0,0] op_sel_hi:[1,0,1]" \
        : "+v"(acc) : "v"(w), "v"(s2))
// Same but broadcasting the HIGH half of the pair operand.
#define PKFMA_HI(acc, w, s2) \
    asm("v_pk_fma_f32 %0, %1, %2, %0 op_sel:[0,1,0] op_sel_hi:[1,1,1]" \
        : "+v"(acc) : "v"(w), "v"(s2))
// Packed mul, broadcasting low half of src1 (chain-head init, saves movs)
#define PKMUL_LO(dst, w, s2) \
    asm("v_pk_mul_f32 %0, %1, %2 op_sel:[0,0] op_sel_hi:[1,0]" \
        : "=v"(dst) : "v"(w), "v"(s2))
// Packed mul, broadcasting HIGH half of src1
#define PKMUL_HI(dst, w, s2) \
    asm("v_pk_mul_f32 %0, %1, %2 op_sel:[0,1] op_sel_hi:[1,1]" \
        : "=v"(dst) : "v"(w), "v"(s2))

__device__ __forceinline__ float fexp2(float x) { return __builtin_amdgcn_exp2f(x); }
__device__ __forceinline__ float frcp(float x)  { return __builtin_amdgcn_rcpf(x); }

// async global -> LDS, 16B per active lane, dest = uniform base + lane*16
__device__ __forceinline__ void gload_lds16(const float* g, float* l) {
    __builtin_amdgcn_global_load_lds(
        (const __attribute__((address_space(1))) unsigned int*)g,
        (__attribute__((address_space(3))) unsigned int*)l,
        16, 0, 0);
}

__global__ __attribute__((amdgpu_waves_per_eu(2, 2))) __launch_bounds__(64)
void rnncf_kernel(const float* __restrict__ x,          // (NVEH, NT, 12)
                  const float* __restrict__ init_state, // (NVEH, 2)
                  const float* __restrict__ hs,         // (2, NVEH, 20)
                  const float* __restrict__ K,          // (12, 80)
                  const float* __restrict__ R,          // (20, 80)
                  const float* __restrict__ bias,       // (80)
                  const float* __restrict__ W2,         // (20, 10)
                  const float* __restrict__ b2,         // (10)
                  const float* __restrict__ Wlc,        // (10, 3)
                  const float* __restrict__ blc,        // (3)
                  const float* __restrict__ W1,         // (10, 1)
                  const float* __restrict__ b1,         // (1)
                  float* __restrict__ out)
{
    const int lane = threadIdx.x;
    const int grp  = lane / 20;     // 0..2 = vehicle slot, 3 = idle lanes 60..63
    const int sub  = lane % 20;     // unit index / head index
    const int veh  = blockIdx.x * 3 + grp;
    const bool active = (grp < 3) && (veh < NVEH);
    const int vs = active ? veh : 0;

    __shared__ __align__(16) float x_lds[8][4][12];   // depth-8 x FIFO
    __shared__ __align__(16) float h_lds[4][20];
    __shared__ __align__(16) float x2_lds[4][12];

    // ---- per-lane weights as (gate-pair) f32x2, PRE-SCALED by the gate's
    // exp2 constant: i,f,o -> -log2(e), g -> +2*log2(e).
    const float s01l = -1.4426950408889634f;   // i
    const float s01h = -1.4426950408889634f;   // f
    const float s23l =  2.8853900817779268f;   // g
    const float s23h = -1.4426950408889634f;   // o
    f32x2 K01[12], K23[12], R01[20], R23[20], bz01, bz23;
    bz01[0] = s01l * bias[sub];      bz01[1] = s01h * bias[20 + sub];
    bz23[0] = s23l * bias[40 + sub]; bz23[1] = s23h * bias[60 + sub];
#pragma unroll
    for (int k = 0; k < 12; ++k) {
        K01[k][0] = s01l * K[k * 80 + sub];      K01[k][1] = s01h * K[k * 80 + 20 + sub];
        K23[k][0] = s23l * K[k * 80 + 40 + sub]; K23[k][1] = s23h * K[k * 80 + 60 + sub];
    }
#pragma unroll
    for (int k = 0; k < 20; ++k) {
        R01[k][0] = s01l * R[k * 80 + sub];      R01[k][1] = s01h * R[k * 80 + 20 + sub];
        R23[k][0] = s23l * R[k * 80 + 40 + sub]; R23[k][1] = s23h * R[k * 80 + 60 + sub];
    }
    const int mh = (sub < 10) ? sub : 9;
    f32x2 W2p[10];
#pragma unroll
    for (int u = 0; u < 10; ++u) {
        W2p[u][0] = W2[(2 * u) * 10 + mh];
        W2p[u][1] = W2[(2 * u + 1) * 10 + mh];
    }
    float b2s = b2[mh];
    const int jl = (sub < 3) ? sub : 0;
    f32x2 Wlcp[5];
#pragma unroll
    for (int m = 0; m < 5; ++m) {
        Wlcp[m][0] = Wlc[(2 * m) * 3 + jl];
        Wlcp[m][1] = Wlc[(2 * m + 1) * 3 + jl];
    }
    float blcs = blc[jl];
    // pin so the compiler cannot sink these loads into the loop
    PIN(bz01); PIN(bz23);
#pragma unroll
    for (int k = 0; k < 12; ++k) { PIN(K01[k]); PIN(K23[k]); }
#pragma unroll
    for (int k = 0; k < 20; ++k) { PIN(R01[k]); PIN(R23[k]); }
#pragma unroll
    for (int u = 0; u < 10; ++u) PIN(W2p[u]);
#pragma unroll
    for (int m = 0; m < 5; ++m) PIN(Wlcp[m]);
    PIN(b2s); PIN(blcs);

    // ---- state ----
    float pos = init_state[vs * 2 + 0];
    float spd = init_state[vs * 2 + 1];
    float c   = hs[(size_t)NVEH * UNITS + (size_t)vs * UNITS + sub];
    float hnew = hs[(size_t)vs * UNITS + sub];

    h_lds[grp][sub] = hnew;
    __builtin_amdgcn_wave_barrier();
    f32x2 hrp[10];
#pragma unroll
    for (int q = 0; q < 5; ++q) {
        float4 v = ((const float4*)&h_lds[grp][0])[q];
        hrp[2*q][0]   = v.x; hrp[2*q][1]   = v.y;
        hrp[2*q+1][0] = v.z; hrp[2*q+1][1] = v.w;
    }
    __builtin_amdgcn_wave_barrier();

    // ---- deep x FIFO: lanes 0..8 stage 16B/step directly into LDS ----
    const bool stg = (lane < 9);
    int sveh = blockIdx.x * 3 + lane / 3;
    if (sveh > NVEH - 1) sveh = NVEH - 1;
    const float* sgp = x + (size_t)sveh * NT * INW + (lane % 3) * 4;

    if (stg) {
#pragma unroll
        for (int t0 = 0; t0 < 8; ++t0)
            gload_lds16(sgp + (size_t)t0 * INW, &x_lds[t0][0][0]);
    }

    float* trajp = out + (size_t)vs * NT;
    float* lcp   = out + (size_t)NVEH * NT + (size_t)vs * NT * 3;

    for (int tb = 0; tb < NT; tb += 4) {
        // loads for steps tb..tb+3 were issued >=1 full block ago; allow the
        // newest 4 (next block's loads) to stay in flight. Never drains to 0.
        asm volatile("s_waitcnt vmcnt(4)" ::: "memory");

#pragma unroll
        for (int j = 0; j < 4; ++j) {
            const int t = tb + j;
            // NOTE: no wave_barriers in this body. Block = 1 wave; the
            // compiler preserves same-wave LDS write->read order on
            // may-aliasing addresses, and the LDS pipe executes a wave's
            // ops in order. Fences only served to serialize the schedule.

            // 1. read raw x_t (per-group broadcast) + deferred-head x2 read
            float4 u0 = ((const float4*)&x_lds[t & 7][grp][0])[0];
            float4 u1 = ((const float4*)&x_lds[t & 7][grp][0])[1];
            float4 u2 = ((const float4*)&x_lds[t & 7][grp][0])[2];
            f32x2 x2p[5];
            if (t > 0) {
#pragma unroll
                for (int q = 0; q < 5; ++q)
                    x2p[q] = ((const f32x2*)&x2_lds[grp][0])[q];
            }

            // 2. transform raw x -> inp pairs (inputs NaN-free)
            const float pp = pos * 0.01f;
            f32x2 inp2[6];
            inp2[0][0] = fmaf(u0.x,  0.01f, -pp); inp2[0][1] = fmaf(u0.y,  0.01f, -pp);
            inp2[1][0] = fmaf(u0.z,  0.01f, -pp); inp2[1][1] = fmaf(u0.w, -0.01f,  pp);
            inp2[2][0] = fmaf(u1.x, -0.01f,  pp); inp2[2][1] = fmaf(u1.y, -0.01f,  pp);
            inp2[3][0] = u1.z * 0.025f;           inp2[3][1] = u1.w * 0.025f;
            inp2[4][0] = u2.x * 0.025f;           inp2[4][1] = u2.y * 0.025f;
            inp2[5][0] = u2.z * 0.025f;           inp2[5][1] = u2.w * 0.025f;

            // 3. gate pre-activations. K-part: one chain per pair (x-only,
            //    off the h-critical path). R-part: FOUR independent 5-deep
            //    chains per pair (even/odd h x two halves) for ILP after
            //    the h exchange.
            f32x2 zK01 = bz01, zK23 = bz23;
#pragma unroll
            for (int q = 0; q < 6; ++q) {
                PKFMA_LO(zK01, K01[2*q],   inp2[q]);
                PKFMA_LO(zK23, K23[2*q],   inp2[q]);
                PKFMA_HI(zK01, K01[2*q+1], inp2[q]);
                PKFMA_HI(zK23, K23[2*q+1], inp2[q]);
            }
            f32x2 cE01, cO01, cE23, cO23;   // first-half chains (h0..h9)
            f32x2 dE01, dO01, dE23, dO23;   // second-half chains (h10..h19)
            PKMUL_LO(cE01, R01[0], hrp[0]);
            PKMUL_HI(cO01, R01[1], hrp[0]);
            PKMUL_LO(cE23, R23[0], hrp[0]);
            PKMUL_HI(cO23, R23[1], hrp[0]);
            PKMUL_LO(dE01, R01[10], hrp[5]);
            PKMUL_HI(dO01, R01[11], hrp[5]);
            PKMUL_LO(dE23, R23[10], hrp[5]);
            PKMUL_HI(dO23, R23[11], hrp[5]);
#pragma unroll
            for (int q = 1; q < 5; ++q) {
                PKFMA_LO(cE01, R01[2*q],   hrp[q]);
                PKFMA_HI(cO01, R01[2*q+1], hrp[q]);
                PKFMA_LO(cE23, R23[2*q],   hrp[q]);
                PKFMA_HI(cO23, R23[2*q+1], hrp[q]);
                PKFMA_LO(dE01, R01[2*q+10], hrp[q+5]);
                PKFMA_HI(dO01, R01[2*q+11], hrp[q+5]);
                PKFMA_LO(dE23, R23[2*q+10], hrp[q+5]);
                PKFMA_HI(dO23, R23[2*q+11], hrp[q+5]);
            }
            f32x2 z01 = (zK01 + (cE01 + cO01)) + (dE01 + dO01);
            f32x2 z23 = (zK23 + (cE23 + cO23)) + (dE23 + dO23);

            // 4. deferred head finish: acc(t-1) -> spd_t (W1/b1 via SGPRs)
            if (t > 0) {
                float a0 = b1[0], a1 = 0.0f;
#pragma unroll
                for (int m = 0; m < 5; ++m) {
                    a0 = fmaf(x2p[m][0], W1[2*m],   a0);
                    a1 = fmaf(x2p[m][1], W1[2*m+1], a1);
                }
                float accr = a0 + a1;
                spd = fmaf(0.1f, fmaf(10.0f, accr, -6.0f), spd);
                if (active && sub < 3) {
                    f32x2 lc2; lc2[0] = blcs; lc2[1] = 0.0f;
#pragma unroll
                    for (int m = 0; m < 5; ++m) {
                        asm("v_pk_fma_f32 %0, %1, %2, %0"
                            : "+v"(lc2) : "v"(x2p[m]), "v"(Wlcp[m]));
                    }
                    lcp[(t - 1) * 3 + sub] = lc2[0] + lc2[1];
                }
            }

            // 5. cell update (weights pre-scaled: exp2 args ready)
            float ig = frcp(1.0f + fexp2(z01[0]));
            float fg = frcp(1.0f + fexp2(z01[1]));
            float gg = 1.0f - 2.0f * frcp(fexp2(z23[0]) + 1.0f);
            float og = frcp(1.0f + fexp2(z23[1]));
            c = fmaf(fg, c, ig * gg);
            float th = 1.0f - 2.0f * frcp(fexp2(2.8853900817779268f * c) + 1.0f);
            hnew = og * th;

            // 6. pos update + traj output (uses spd_t)
            float posn = fmaf(0.1f, spd, pos);
            if (active && sub == 0) trajp[t] = posn;
            pos = posn;

            // 7. share h_new, reload into packed regs
            h_lds[grp][sub] = hnew;
#pragma unroll
            for (int q = 0; q < 5; ++q) {
                float4 v = ((const float4*)&h_lds[grp][0])[q];
                hrp[2*q][0]   = v.x; hrp[2*q][1]   = v.y;
                hrp[2*q+1][0] = v.z; hrp[2*q+1][1] = v.w;
            }

            // 8. head part 1: xm = relu(h . W2[:,mh] + b2[mh]); exchanged next iter
            f32x2 xm2; xm2[0] = b2s; xm2[1] = 0.0f;
#pragma unroll
            for (int u = 0; u < 10; ++u) {
                asm("v_pk_fma_f32 %0, %1, %2, %0"
                    : "+v"(xm2) : "v"(hrp[u]), "v"(W2p[u]));
            }
            float xm = fmaxf(xm2[0] + xm2[1], 0.0f);
            if (sub < 10) x2_lds[grp][sub] = xm;
        }

        // issue loads for steps tb+8 .. tb+11 into the slots just consumed
        if (stg) {
#pragma unroll
            for (int j = 0; j < 4; ++j) {
                int tt = tb + 8 + j; if (tt > NT - 1) tt = NT - 1;
                gload_lds16(sgp + (size_t)tt * INW, &x_lds[(tb + j) & 7][0][0]);
            }
        }
    }

    // ---- epilogue: finish head for step NT-1 ----
    {
        f32x2 x2p[5];
#pragma unroll
        for (int q = 0; q < 5; ++q)
            x2p[q] = ((const f32x2*)&x2_lds[grp][0])[q];
        float a0 = b1[0], a1 = 0.0f;
#pragma unroll
        for (int m = 0; m < 5; ++m) {
            a0 = fmaf(x2p[m][0], W1[2*m],   a0);
            a1 = fmaf(x2p[m][1], W1[2*m+1], a1);
        }
        float accr = a0 + a1;
        spd = fmaf(0.1f, fmaf(10.0f, accr, -6.0f), spd);
        if (active && sub < 3) {
            f32x2 lc2; lc2[0] = blcs; lc2[1] = 0.0f;
#pragma unroll
            for (int m = 0; m < 5; ++m) {
                asm("v_pk_fma_f32 %0, %1, %2, %0"
                    : "+v"(lc2) : "v"(x2p[m]), "v"(Wlcp[m]));
            }
            lcp[(NT - 1) * 3 + sub] = lc2[0] + lc2[1];
        }
    }

    if (active) {
        float* spdf = out + (size_t)NVEH * NT * 4;
        float* hf   = spdf + NVEH;
        float* cf   = hf + (size_t)NVEH * UNITS;
        if (sub == 0) spdf[veh] = spd;
        hf[(size_t)veh * UNITS + sub] = hnew;
        cf[(size_t)veh * UNITS + sub] = c;
    }
}

extern "C" void kernel_launch(void* const* d_in, const int* in_sizes, int n_in,
                              void* d_out, int out_size, void* d_ws, size_t ws_size,
                              hipStream_t stream) {
    const float* x    = (const float*)d_in[0];
    const float* st0  = (const float*)d_in[1];
    const float* hs   = (const float*)d_in[2];
    const float* K    = (const float*)d_in[3];
    const float* R    = (const float*)d_in[4];
    const float* bias = (const float*)d_in[5];
    const float* W2   = (const float*)d_in[6];
    const float* b2   = (const float*)d_in[7];
    const float* Wlc  = (const float*)d_in[8];
    const float* blc  = (const float*)d_in[9];
    const float* W1   = (const float*)d_in[10];
    const float* b1   = (const float*)d_in[11];
    float* out = (float*)d_out;

    dim3 grid((NVEH + 2) / 3);   // 1366 blocks, 3 vehicles each
    dim3 block(64);
    hipLaunchKernelGGL(rnncf_kernel, grid, block, 0, stream,
                       x, st0, hs, K, R, bias, W2, b2, Wlc, blc, W1, b1, out);
}